// Round 1
// 287.916 us; speedup vs baseline: 1.0026x; 1.0026x over previous
//
#include <hip/hip_runtime.h>
#include <math.h>

#define HDIM 2048
#define NMB  512

// workspace layout (floats)
#define WS_GATES 0          // gf, gw, add, erase
#define WS_FRF   4          // 512
#define WS_WRF   516        // 12800
#define WS_FWF   13316      // 512
#define WS_WWF   13828      // 12800
#define WS_MWF   26628      // 100
#define WS_MWW   26728      // 196
#define WS_FOC   26924      // 100
#define WS_WIDE  27024      // 36

// out layout (floats)
#define OUT_READ 0          // 2048
#define OUT_FRF  2048       // 512
#define OUT_WRF  2560       // 12800
#define OUT_FWF  15360      // 512
#define OUT_WWF  15872      // 12800
#define OUT_MT   28672      // 51200

#define NROWS (4 + 512 + 12800 + 512 + 12800 + 100 + 196)  // 26924
#define NQUADS (NROWS / 4)                                 // 6731

typedef float vfloat4 __attribute__((ext_vector_type(4)));

__device__ __forceinline__ vfloat4 mix4(vfloat4 a, vfloat4 c, float g) {
    return a * g + c * (1.0f - g);
}

// 4 rows per wave: 32 nontemporal 1-KB loads in flight, h amortized over 4 rows.
__global__ __launch_bounds__(256) void k1_gemv(
    const float* __restrict__ h,
    const float* __restrict__ w_fg, const float* __restrict__ b_fg,
    const float* __restrict__ w_wg, const float* __restrict__ b_wg,
    const float* __restrict__ w_ag, const float* __restrict__ b_ag,
    const float* __restrict__ w_eg, const float* __restrict__ b_eg,
    const float* __restrict__ w_hrf, const float* __restrict__ b_hrf,
    const float* __restrict__ w_hrw, const float* __restrict__ b_hrw,
    const float* __restrict__ w_hwf, const float* __restrict__ b_hwf,
    const float* __restrict__ w_hww, const float* __restrict__ b_hww,
    const float* __restrict__ w_hfc, const float* __restrict__ b_hfc,
    const float* __restrict__ w_hwc, const float* __restrict__ b_hwc,
    float* __restrict__ ws)
{
    const int lane = threadIdx.x & 63;
    const int g    = (blockIdx.x * blockDim.x + threadIdx.x) >> 6;
    if (g >= NQUADS) return;

    // h loaded once per wave into registers (normal cached loads — L1/L2-resident)
    const vfloat4* h4 = (const vfloat4*)h;
    vfloat4 hv[8];
#pragma unroll
    for (int s = 0; s < 8; ++s) hv[s] = h4[(s << 6) + lane];

    const int r0 = g * 4;

    const float* wp[4];
    float bias[4];
    int act[4];
    float* outp[4];
#pragma unroll
    for (int t = 0; t < 4; ++t) {
        int r = r0 + t;
        if (r < 4) {
            const float* w; const float* b;
            if (r == 0)      { w = w_fg; b = b_fg; }
            else if (r == 1) { w = w_wg; b = b_wg; }
            else if (r == 2) { w = w_ag; b = b_ag; }
            else             { w = w_eg; b = b_eg; }
            wp[t] = w; bias[t] = b[0]; act[t] = (r < 2) ? 0 : 1;
            outp[t] = ws + WS_GATES + r;
        } else if (r < 516) {
            int k = r - 4;
            wp[t] = w_hrf + (size_t)k * HDIM; bias[t] = b_hrf[k]; act[t] = 1;
            outp[t] = ws + WS_FRF + k;
        } else if (r < 13316) {
            int k = r - 516;
            wp[t] = w_hrw + (size_t)k * HDIM; bias[t] = b_hrw[k]; act[t] = 1;
            outp[t] = ws + WS_WRF + k;
        } else if (r < 13828) {
            int k = r - 13316;
            wp[t] = w_hwf + (size_t)k * HDIM; bias[t] = b_hwf[k]; act[t] = 1;
            outp[t] = ws + WS_FWF + k;
        } else if (r < 26628) {
            int k = r - 13828;
            wp[t] = w_hww + (size_t)k * HDIM; bias[t] = b_hww[k]; act[t] = 1;
            outp[t] = ws + WS_WWF + k;
        } else if (r < 26728) {
            int k = r - 26628;
            wp[t] = w_hfc + (size_t)k * HDIM; bias[t] = b_hfc[k]; act[t] = 2;
            outp[t] = ws + WS_MWF + k;
        } else {
            int k = r - 26728;
            wp[t] = w_hwc + (size_t)k * HDIM; bias[t] = b_hwc[k]; act[t] = 2;
            outp[t] = ws + WS_MWW + k;
        }
    }

    const vfloat4* wA = (const vfloat4*)wp[0];
    const vfloat4* wB = (const vfloat4*)wp[1];
    const vfloat4* wC = (const vfloat4*)wp[2];
    const vfloat4* wD = (const vfloat4*)wp[3];

    // 32 nontemporal weight loads issued back-to-back (4 rows in flight)
    vfloat4 av[8], bv[8], cv[8], dv[8];
#pragma unroll
    for (int s = 0; s < 8; ++s)
        av[s] = __builtin_nontemporal_load(&wA[(s << 6) + lane]);
#pragma unroll
    for (int s = 0; s < 8; ++s)
        bv[s] = __builtin_nontemporal_load(&wB[(s << 6) + lane]);
#pragma unroll
    for (int s = 0; s < 8; ++s)
        cv[s] = __builtin_nontemporal_load(&wC[(s << 6) + lane]);
#pragma unroll
    for (int s = 0; s < 8; ++s)
        dv[s] = __builtin_nontemporal_load(&wD[(s << 6) + lane]);

    float acc0 = 0.f, acc1 = 0.f, acc2 = 0.f, acc3 = 0.f;
#pragma unroll
    for (int s = 0; s < 8; ++s) {
        acc0 += av[s].x * hv[s].x + av[s].y * hv[s].y + av[s].z * hv[s].z + av[s].w * hv[s].w;
        acc1 += bv[s].x * hv[s].x + bv[s].y * hv[s].y + bv[s].z * hv[s].z + bv[s].w * hv[s].w;
        acc2 += cv[s].x * hv[s].x + cv[s].y * hv[s].y + cv[s].z * hv[s].z + cv[s].w * hv[s].w;
        acc3 += dv[s].x * hv[s].x + dv[s].y * hv[s].y + dv[s].z * hv[s].z + dv[s].w * hv[s].w;
    }
#pragma unroll
    for (int off = 32; off > 0; off >>= 1) {
        acc0 += __shfl_down(acc0, off);
        acc1 += __shfl_down(acc1, off);
        acc2 += __shfl_down(acc2, off);
        acc3 += __shfl_down(acc3, off);
    }

    if (lane == 0) {
        float accs[4] = {acc0, acc1, acc2, acc3};
#pragma unroll
        for (int t = 0; t < 4; ++t) {
            float x = accs[t] + bias[t];
            float y;
            if (act[t] == 0) {
                float s = 1.f / (1.f + __expf(-x));
                y = fminf(fmaxf(1.2f * s - 0.1f, 0.f), 1.f);
            } else if (act[t] == 1) {
                y = fminf(fmaxf(x, 0.f), 1.f);
            } else {
                y = fmaxf(x, 0.f);
            }
            *outp[t] = y;
        }
    }
}

// block 0..25    : elementwise gate-mix (float4) -> outputs frf_t / wrf_t / fwf_t / wwf_t
// block 26       : focused (100 outputs, reduce over 512 channels)
// block 27..62   : wide conv (36 outputs, reduce over 12800 taps)
// block 63..262  : m_t (51200 outputs, 25-tap conv each)
__global__ __launch_bounds__(256) void k2_mix_conv(
    const float* __restrict__ frf, const float* __restrict__ wrf,
    const float* __restrict__ fwf, const float* __restrict__ wwf,
    const float* __restrict__ m,
    float* __restrict__ ws, float* __restrict__ out)
{
    const float gf = ws[WS_GATES + 0];
    const float gw = ws[WS_GATES + 1];
    const float addg = ws[WS_GATES + 2];
    const float erg  = ws[WS_GATES + 3];
    const int b = blockIdx.x;
    const int tid = threadIdx.x;

    if (b < 26) {
        int e = (b * 256 + tid) * 4;   // < 26624; all region boundaries are /4
        if (e < 512) {
            vfloat4 a = *(const vfloat4*)(ws + WS_FRF + e);
            vfloat4 c = *(const vfloat4*)(frf + e);
            *(vfloat4*)(out + OUT_FRF + e) = mix4(a, c, gf);
        } else if (e < 13312) {
            int k = e - 512;
            vfloat4 a = *(const vfloat4*)(ws + WS_WRF + k);
            vfloat4 c = *(const vfloat4*)(wrf + k);
            *(vfloat4*)(out + OUT_WRF + k) = mix4(a, c, gw);
        } else if (e < 13824) {
            int k = e - 13312;
            vfloat4 a = *(const vfloat4*)(ws + WS_FWF + k);
            vfloat4 c = *(const vfloat4*)(fwf + k);
            *(vfloat4*)(out + OUT_FWF + k) = mix4(a, c, gf);
        } else {
            int k = e - 13824;
            vfloat4 a = *(const vfloat4*)(ws + WS_WWF + k);
            vfloat4 c = *(const vfloat4*)(wwf + k);
            *(vfloat4*)(out + OUT_WWF + k) = mix4(a, c, gw);
        }
    } else if (b == 26) {
        __shared__ float sfrf[512];
        for (int e = tid; e < 512; e += 256)
            sfrf[e] = ws[WS_FRF + e] * gf + frf[e] * (1.f - gf);
        __syncthreads();
        if (tid < 100) {
            float acc = 0.f;
            for (int c = 0; c < 512; ++c) acc += sfrf[c] * m[c * 100 + tid];
            ws[WS_FOC + tid] = fmaxf(acc, 0.f);
        }
    } else if (b < 63) {
        int o = b - 27;
        int i = o / 6, j = o % 6;
        float acc = 0.f;
        for (int k = tid; k < 12800; k += 256) {
            int c = k / 25, pq = k % 25, p = pq / 5, q = pq % 5;
            float wm = ws[WS_WRF + k] * gw + wrf[k] * (1.f - gw);
            acc += wm * m[c * 100 + (i + p) * 10 + (j + q)];
        }
        __shared__ float red[256];
        red[tid] = acc;
        __syncthreads();
        for (int s = 128; s > 0; s >>= 1) {
            if (tid < s) red[tid] += red[tid + s];
            __syncthreads();
        }
        if (tid == 0) ws[WS_WIDE + o] = fmaxf(red[0], 0.f);
    } else {
        __shared__ float smwf[100];
        __shared__ float smww[196];
        if (tid < 100) smwf[tid] = ws[WS_MWF + tid];
        if (tid < 196) smww[tid] = ws[WS_MWW + tid];
        __syncthreads();
        int t = (b - 63) * 256 + tid;   // < 51200
        int c = t / 100, hw = t % 100;
        int i = hw / 10, j = hw % 10;
        float fwf_t = ws[WS_FWF + c] * gf + fwf[c] * (1.f - gf);
        float wwacc = 0.f;
#pragma unroll
        for (int p = 0; p < 5; ++p) {
#pragma unroll
            for (int q = 0; q < 5; ++q) {
                int k = c * 25 + p * 5 + q;
                float wm = ws[WS_WWF + k] * gw + wwf[k] * (1.f - gw);
                wwacc += wm * smww[(i + p) * 14 + (j + q)];
            }
        }
        out[OUT_MT + t] = m[t] + (smwf[hw] * fwf_t + wwacc) * (1.f - erg) + 2.f * addg;
    }
}

__global__ __launch_bounds__(256) void k3_read(
    const float* __restrict__ w_cfr, const float* __restrict__ b_cfr,
    const float* __restrict__ w_cwr, const float* __restrict__ b_cwr,
    const float* __restrict__ ws, float* __restrict__ out)
{
    const int wave = (blockIdx.x * blockDim.x + threadIdx.x) >> 6;
    const int lane = threadIdx.x & 63;
    if (wave >= 2048) return;
    const float* foc = ws + WS_FOC;
    const float* wid = ws + WS_WIDE;

    float af = w_cfr[wave * 100 + lane] * foc[lane];     // lane in [0,64) < 100
    int k2 = lane + 64;
    if (k2 < 100) af += w_cfr[wave * 100 + k2] * foc[k2];
    float aw = (lane < 36) ? w_cwr[wave * 36 + lane] * wid[lane] : 0.f;
#pragma unroll
    for (int off = 32; off > 0; off >>= 1) {
        af += __shfl_down(af, off);
        aw += __shfl_down(aw, off);
    }
    if (lane == 0)
        out[wave] = (aw + b_cwr[wave]) + fmaxf(af + b_cfr[wave], 0.f);
}

extern "C" void kernel_launch(void* const* d_in, const int* in_sizes, int n_in,
                              void* d_out, int out_size, void* d_ws, size_t ws_size,
                              hipStream_t stream) {
    const float* h_t  = (const float*)d_in[0];
    const float* frf  = (const float*)d_in[1];
    const float* wrf  = (const float*)d_in[2];
    const float* fwf  = (const float*)d_in[3];
    const float* wwf  = (const float*)d_in[4];
    const float* m    = (const float*)d_in[5];
    const float* w_fg = (const float*)d_in[6];  const float* b_fg = (const float*)d_in[7];
    const float* w_wg = (const float*)d_in[8];  const float* b_wg = (const float*)d_in[9];
    const float* w_hrf= (const float*)d_in[10]; const float* b_hrf= (const float*)d_in[11];
    const float* w_hrw= (const float*)d_in[12]; const float* b_hrw= (const float*)d_in[13];
    const float* w_cfr= (const float*)d_in[14]; const float* b_cfr= (const float*)d_in[15];
    const float* w_cwr= (const float*)d_in[16]; const float* b_cwr= (const float*)d_in[17];
    const float* w_hfc= (const float*)d_in[18]; const float* b_hfc= (const float*)d_in[19];
    const float* w_hwc= (const float*)d_in[20]; const float* b_hwc= (const float*)d_in[21];
    const float* w_ag = (const float*)d_in[22]; const float* b_ag = (const float*)d_in[23];
    const float* w_eg = (const float*)d_in[24]; const float* b_eg = (const float*)d_in[25];
    const float* w_hwf= (const float*)d_in[26]; const float* b_hwf= (const float*)d_in[27];
    const float* w_hww= (const float*)d_in[28]; const float* b_hww= (const float*)d_in[29];

    float* out = (float*)d_out;
    float* ws  = (float*)d_ws;

    // K1: all h-projections, 4 rows in flight per wave, nontemporal weight stream
    {
        int blocks = (NQUADS + 3) / 4;   // 4 waves per 256-thread block
        hipLaunchKernelGGL(k1_gemv, dim3(blocks), dim3(256), 0, stream,
            h_t,
            w_fg, b_fg, w_wg, b_wg, w_ag, b_ag, w_eg, b_eg,
            w_hrf, b_hrf, w_hrw, b_hrw, w_hwf, b_hwf, w_hww, b_hww,
            w_hfc, b_hfc, w_hwc, b_hwc,
            ws);
    }
    // K2: gate-mix + convs + m_t
    hipLaunchKernelGGL(k2_mix_conv, dim3(263), dim3(256), 0, stream,
        frf, wrf, fwf, wwf, m, ws, out);
    // K3: read projection (one wave per row)
    hipLaunchKernelGGL(k3_read, dim3(512), dim3(256), 0, stream,
        w_cfr, b_cfr, w_cwr, b_cwr, ws, out);
}